// Round 2
// baseline (711.269 us; speedup 1.0000x reference)
//
#include <hip/hip_runtime.h>

// VQ codebook lookup: B=4194304 rows, K=10 codes, D=16 dims, fp32.
// Outputs (concatenated in d_out as fp32): z_q_st (B*D), indices (B, as float),
// commitment_loss (1).

constexpr long long NB = 4194304LL; // batch
constexpr int KC = 10;              // num codes
constexpr int DD = 16;              // code dim

__global__ void vq_zero_loss(float* p) { *p = 0.0f; }

__global__ __launch_bounds__(256, 4) void vq_kernel(
    const float* __restrict__ z_e,
    const float* __restrict__ codebook,
    float* __restrict__ zq_out,
    float* __restrict__ idx_out,
    float* __restrict__ loss_out)
{
    __shared__ float sE[KC * DD];
    __shared__ float sN[KC];

    const int tid = threadIdx.x;
    if (tid < KC * DD) sE[tid] = codebook[tid];
    __syncthreads();
    if (tid < KC) {
        // ||e_k||^2, sequential order over d (matches jnp.sum semantics closely)
        float n = 0.f;
#pragma unroll
        for (int d = 0; d < DD; ++d) { float v = sE[tid * DD + d]; n += v * v; }
        sN[tid] = n;
    }
    __syncthreads();

    float loss_acc = 0.f;
    const long long stride = (long long)gridDim.x * blockDim.x;
    for (long long row = (long long)blockIdx.x * blockDim.x + tid; row < NB; row += stride) {
        const float4* zp = reinterpret_cast<const float4*>(z_e + row * DD);
        const float4 z0 = zp[0], z1 = zp[1], z2 = zp[2], z3 = zp[3];

        float zr[DD];
        zr[0] = z0.x; zr[1] = z0.y; zr[2]  = z0.z; zr[3]  = z0.w;
        zr[4] = z1.x; zr[5] = z1.y; zr[6]  = z1.z; zr[7]  = z1.w;
        zr[8] = z2.x; zr[9] = z2.y; zr[10] = z2.z; zr[11] = z2.w;
        zr[12] = z3.x; zr[13] = z3.y; zr[14] = z3.z; zr[15] = z3.w;

        // ||z||^2 sequential over d
        float sumz = 0.f;
#pragma unroll
        for (int d = 0; d < DD; ++d) sumz += zr[d] * zr[d];

        float best = __builtin_inff();
        int bk = 0;
#pragma unroll
        for (int k = 0; k < KC; ++k) {
            // load code row as 4x b128 from LDS (broadcast, conflict-free)
            const float4* ep = reinterpret_cast<const float4*>(sE + k * DD);
            const float4 e0 = ep[0], e1 = ep[1], e2 = ep[2], e3 = ep[3];
            float er[DD];
            er[0] = e0.x; er[1] = e0.y; er[2]  = e0.z; er[3]  = e0.w;
            er[4] = e1.x; er[5] = e1.y; er[6]  = e1.z; er[7]  = e1.w;
            er[8] = e2.x; er[9] = e2.y; er[10] = e2.z; er[11] = e2.w;
            er[12] = e3.x; er[13] = e3.y; er[14] = e3.z; er[15] = e3.w;

            // z . e_k as a sequential fma chain (mimics XLA dot_general)
            float dot = 0.f;
#pragma unroll
            for (int d = 0; d < DD; ++d) dot = fmaf(zr[d], er[d], dot);

            // reference association: (||z||^2 - 2*dot) + ||e||^2
            const float dist = (sumz - 2.0f * dot) + sN[k];
            if (dist < best) { best = dist; bk = k; }  // first-min, matches argmin
        }

        const float4* bp = reinterpret_cast<const float4*>(sE + bk * DD);
        const float4 q0 = bp[0], q1 = bp[1], q2 = bp[2], q3 = bp[3];
        float qr[DD];
        qr[0] = q0.x; qr[1] = q0.y; qr[2]  = q0.z; qr[3]  = q0.w;
        qr[4] = q1.x; qr[5] = q1.y; qr[6]  = q1.z; qr[7]  = q1.w;
        qr[8] = q2.x; qr[9] = q2.y; qr[10] = q2.z; qr[11] = q2.w;
        qr[12] = q3.x; qr[13] = q3.y; qr[14] = q3.z; qr[15] = q3.w;

        // z_q_st = z + (q - z), computed literally (matches straight-through expr)
        float4 o0, o1, o2, o3;
        float* ov = &o0.x; // o0..o3 are contiguous? not guaranteed -> write explicitly
        (void)ov;
        float outv[DD];
#pragma unroll
        for (int d = 0; d < DD; ++d) {
            const float diff = qr[d] - zr[d];
            outv[d] = zr[d] + diff;
            loss_acc = fmaf(diff, diff, loss_acc); // (z-q)^2 == (q-z)^2
        }
        o0.x = outv[0];  o0.y = outv[1];  o0.z = outv[2];  o0.w = outv[3];
        o1.x = outv[4];  o1.y = outv[5];  o1.z = outv[6];  o1.w = outv[7];
        o2.x = outv[8];  o2.y = outv[9];  o2.z = outv[10]; o2.w = outv[11];
        o3.x = outv[12]; o3.y = outv[13]; o3.z = outv[14]; o3.w = outv[15];

        float4* op = reinterpret_cast<float4*>(zq_out + row * DD);
        op[0] = o0; op[1] = o1; op[2] = o2; op[3] = o3;
        idx_out[row] = (float)bk;
    }

    // wave(64) shuffle reduction
#pragma unroll
    for (int off = 32; off > 0; off >>= 1)
        loss_acc += __shfl_down(loss_acc, off);

    __shared__ float wsum[4];
    const int wave = tid >> 6;
    const int lane = tid & 63;
    if (lane == 0) wsum[wave] = loss_acc;
    __syncthreads();
    if (tid == 0) {
        const float s = (wsum[0] + wsum[1] + wsum[2] + wsum[3]) * (1.0f / 67108864.0f); // 1/(B*D), 2^-26 exact
        atomicAdd(loss_out, s);
    }
}

extern "C" void kernel_launch(void* const* d_in, const int* in_sizes, int n_in,
                              void* d_out, int out_size, void* d_ws, size_t ws_size,
                              hipStream_t stream) {
    const float* z_e      = (const float*)d_in[0];
    const float* codebook = (const float*)d_in[1];

    float* out      = (float*)d_out;
    float* zq_out   = out;                 // B*D
    float* idx_out  = out + NB * DD;       // B
    float* loss_out = out + NB * DD + NB;  // 1

    vq_zero_loss<<<1, 1, 0, stream>>>(loss_out);

    // 2048 blocks x 256 threads = 2^19 threads; 4194304/2^19 = 8 rows/thread
    vq_kernel<<<2048, 256, 0, stream>>>(z_e, codebook, zq_out, idx_out, loss_out);
}